// Round 1
// baseline (1249.027 us; speedup 1.0000x reference)
//
#include <hip/hip_runtime.h>
#include <hip/hip_bf16.h>

// Sizes
#define NB 256
#define NS 30
#define NW 10
#define SYM 128
#define HID 512
#define ENT 64
#define ROLE 32

// Workspace offsets (in floats)
static const size_t OF_TPR  = 0;          // 256*8*64*32*8 = 33,554,432 (chunked [b][cf][e][r][8])
static const size_t OF_P    = 33554432;   // 3*256*64*64 = 3,145,728
static const size_t OF_SENT = 36700160;   // 7680*128
static const size_t OF_QEMB = 37683200;   // 256*128
static const size_t OF_H    = 37715968;   // 7680*512 (reused per head)
static const size_t OF_E1   = 41648128;   // 7680*64
static const size_t OF_E2   = 42139648;
static const size_t OF_R1   = 42631168;   // 7680*32
static const size_t OF_R2   = 42876928;
static const size_t OF_R3   = 43122688;
static const size_t OF_QE1  = 43368448;   // 256*64
static const size_t OF_QR1  = 43384832;   // 256*32
static const size_t OF_QR2  = 43393024;
static const size_t OF_QR3  = 43401216;
static const size_t OF_NP   = 43409408;   // 256*8 norm partials
static const size_t OF_SC   = 43411456;   // 3*256 scales

// ---------------- embedding: sent[b,s,e] = sum_w WE[story[b,s,w],e]*PE[w,e] ----------------
__global__ __launch_bounds__(128) void embed_k(const int* __restrict__ story, const int* __restrict__ query,
    const float* __restrict__ WE, const float* __restrict__ PE,
    float* __restrict__ sent, float* __restrict__ qemb) {
  int bs = blockIdx.x; int e = threadIdx.x;
  const int* idx; float* dst;
  if (bs < 7680) { idx = story + (size_t)bs * NW; dst = sent + (size_t)bs * SYM; }
  else           { idx = query + (size_t)(bs - 7680) * NW; dst = qemb + (size_t)(bs - 7680) * SYM; }
  float acc = 0.f;
  #pragma unroll
  for (int w = 0; w < NW; ++w) {
    int t = idx[w];                      // wave-uniform -> s_load
    acc += WE[t * SYM + e] * PE[w * SYM + e];
  }
  dst[e] = acc;
}

// ---------------- MLP stage 1: H = tanh(X[R,128] @ W1[128,512] + b1) ----------------
__global__ __launch_bounds__(256) void mlp_h(const float* __restrict__ X, const float* __restrict__ W1,
    const float* __restrict__ b1, float* __restrict__ Hout) {
  __shared__ float xt[16 * 128];
  int r0 = blockIdx.x * 16;
  int c0 = blockIdx.y * 128;
  int tid = threadIdx.x;
  #pragma unroll
  for (int i = 0; i < 8; ++i) { int idx = tid + i * 256; xt[idx] = X[(size_t)r0 * 128 + idx]; }
  __syncthreads();
  int c = c0 + (tid & 127); int grp = tid >> 7;   // 2 row-groups of 8 rows
  float acc[8] = {};
  for (int k = 0; k < 128; ++k) {
    float w = W1[k * 512 + c];
    #pragma unroll
    for (int i = 0; i < 8; ++i) acc[i] += xt[(grp * 8 + i) * 128 + k] * w;
  }
  float bb = b1[c];
  #pragma unroll
  for (int i = 0; i < 8; ++i)
    Hout[(size_t)(r0 + grp * 8 + i) * 512 + c] = tanhf(acc[i] + bb);
}

// ---------------- MLP stage 2: Out = tanh(H[R,512] @ W2[512,O] + b2) ----------------
template <int O>
__global__ __launch_bounds__(256) void mlp_o(const float* __restrict__ H, const float* __restrict__ W2,
    const float* __restrict__ b2, float* __restrict__ Out) {
  __shared__ float ht[16 * 512];
  int r0 = blockIdx.x * 16; int tid = threadIdx.x;
  #pragma unroll
  for (int i = 0; i < 32; ++i) { int idx = tid + i * 256; ht[idx] = H[(size_t)r0 * 512 + idx]; }
  __syncthreads();
  const int G = 256 / O;     // groups
  const int RPG = 16 / G;    // rows per group
  int c = tid % O; int grp = tid / O;
  float acc[RPG] = {};
  for (int k = 0; k < 512; ++k) {
    float w = W2[k * O + c];
    #pragma unroll
    for (int i = 0; i < RPG; ++i) acc[i] += ht[(grp * RPG + i) * 512 + k] * w;
  }
  float bb = b2[c];
  #pragma unroll
  for (int i = 0; i < RPG; ++i)
    Out[(size_t)(r0 + grp * RPG + i) * O + c] = tanhf(acc[i] + bb);
}

// ---------------- TPR layer kernel ----------------
// Block = (b, cf): owns f-columns [cf*8, cf*8+8). Thread (r = tid>>3, f = tid&7) keeps
// T[e] (the f,r column over all 64 e) in registers for the whole layer.
// LAYER 0 reads fwm (broadcast init); LAYER>0 reads chunked tpr * deferred scale.
// LAYER 2 additionally emits P_k[e,f] = sum_r qr_k[r]*T[e,r,f] and skips the tpr write.
template <int LAYER>
__global__ __launch_bounds__(256, 2) void layer_k(
    const float* __restrict__ fwm, float* __restrict__ tpr,
    const float* __restrict__ e1g, const float* __restrict__ e2g,
    const float* __restrict__ r1g, const float* __restrict__ r2g, const float* __restrict__ r3g,
    const float* __restrict__ qr1g, const float* __restrict__ qr2g, const float* __restrict__ qr3g,
    const float* __restrict__ scaleIn, float* __restrict__ normPartial, float* __restrict__ Pout) {
  __shared__ float e1b[1920], e2b[1920];          // [s][64]
  __shared__ float r1b[990], r2b[990], r3b[990];  // [s][33] padded
  __shared__ float tb[7710];                      // [s][257] padded (also reused for P staging)
  __shared__ float wbuf[240], mbuf[240];          // hats [s][8]
  __shared__ float qr[96];
  __shared__ float red[4];
  int b = blockIdx.y, cf = blockIdx.x, tid = threadIdx.x;
  int f0 = cf * 8;
  int r = tid >> 3, f = tid & 7;

  for (int i = tid; i < 1920; i += 256) {
    e1b[i] = e1g[(size_t)b * 1920 + i];
    e2b[i] = e2g[(size_t)b * 1920 + i];
  }
  for (int i = tid; i < 960; i += 256) {
    int s = i >> 5, rr = i & 31;
    r1b[s * 33 + rr] = r1g[(size_t)b * 960 + i];
    r2b[s * 33 + rr] = r2g[(size_t)b * 960 + i];
    r3b[s * 33 + rr] = r3g[(size_t)b * 960 + i];
  }
  if (LAYER == 2 && tid < 32) {
    qr[tid]      = qr1g[b * 32 + tid];
    qr[32 + tid] = qr2g[b * 32 + tid];
    qr[64 + tid] = qr3g[b * 32 + tid];
  }

  float T[64];
  float* chunk = tpr + ((size_t)b * 8 + cf) * 16384;
  if (LAYER == 0) {
    #pragma unroll
    for (int e = 0; e < 64; ++e) T[e] = fwm[e * 2048 + r * 64 + f0 + f];
  } else {
    float sc = scaleIn[b];
    #pragma unroll
    for (int e = 0; e < 64; ++e) T[e] = chunk[e * 256 + tid] * sc;
  }
  __syncthreads();

  // t[s,r,f] = sum_e esrc[s,e] * T[e]
  auto phaseA = [&](const float* esrc) {
    for (int s = 0; s < 30; s += 2) {
      float a0 = 0.f, a1 = 0.f;
      const float4* v0 = reinterpret_cast<const float4*>(esrc + s * 64);
      const float4* v1 = reinterpret_cast<const float4*>(esrc + s * 64 + 64);
      #pragma unroll
      for (int i = 0; i < 16; ++i) {
        float4 w0 = v0[i], w1 = v1[i];
        a0 += w0.x * T[4*i] + w0.y * T[4*i+1] + w0.z * T[4*i+2] + w0.w * T[4*i+3];
        a1 += w1.x * T[4*i] + w1.y * T[4*i+1] + w1.z * T[4*i+2] + w1.w * T[4*i+3];
      }
      tb[s * 257 + tid] = a0; tb[(s + 1) * 257 + tid] = a1;
    }
    __syncthreads();
  };
  // hat[s,f] = sum_r rsrc[s,r] * t[s,r,f]
  auto phaseB = [&](const float* rsrc, float* hat) {
    if (tid < 240) {
      int s = tid >> 3, ff = tid & 7; float a = 0.f;
      #pragma unroll
      for (int rr = 0; rr < 32; ++rr) a += rsrc[s * 33 + rr] * tb[s * 257 + rr * 8 + ff];
      hat[tid] = a;
    }
    __syncthreads();
  };
  // T[e] += sum_s esrc[s,e] * u[s]
  auto update = [&](const float* esrc, float u, int s) {
    const float4* ev = reinterpret_cast<const float4*>(esrc + s * 64);
    #pragma unroll
    for (int i = 0; i < 16; ++i) {
      float4 w = ev[i];
      T[4*i] += w.x * u; T[4*i+1] += w.y * u; T[4*i+2] += w.z * u; T[4*i+3] += w.w * u;
    }
  };

  // ---- write op ----
  phaseA(e1b);
  phaseB(r1b, wbuf);                       // w_hat
  for (int s = 0; s < 30; ++s) {
    float u = r1b[s * 33 + r] * (e2b[s * 64 + f0 + f] - wbuf[s * 8 + f]);
    update(e1b, u, s);
  }
  // ---- move op ----
  phaseA(e1b);
  phaseB(r2b, mbuf);                       // m_hat
  for (int s = 0; s < 30; ++s) {
    float u = r2b[s * 33 + r] * (wbuf[s * 8 + f] - mbuf[s * 8 + f]);
    update(e1b, u, s);
  }
  // ---- backlink op ----
  phaseA(e2b);
  phaseB(r3b, wbuf);                       // b_hat (reuses wbuf)
  for (int s = 0; s < 30; ++s) {
    float u = r3b[s * 33 + r] * (e1b[s * 64 + f0 + f] - wbuf[s * 8 + f]);
    update(e2b, u, s);
  }

  // ---- norm partial (deterministic, no atomics) ----
  float local = 0.f;
  #pragma unroll
  for (int e = 0; e < 64; ++e) local += T[e] * T[e];
  #pragma unroll
  for (int o = 32; o > 0; o >>= 1) local += __shfl_down(local, o);
  if ((tid & 63) == 0) red[tid >> 6] = local;
  __syncthreads();
  if (tid == 0) normPartial[(size_t)b * 8 + cf] = red[0] + red[1] + red[2] + red[3];

  if (LAYER < 2) {
    #pragma unroll
    for (int e = 0; e < 64; ++e) chunk[e * 256 + tid] = T[e];
  } else {
    // P_k[e, f0+f] = sum_r qr_k[r] * T[e,r,f]   (stage T through LDS in two e-halves)
    #pragma unroll
    for (int half = 0; half < 2; ++half) {
      __syncthreads();
      #pragma unroll
      for (int e = 0; e < 32; ++e) tb[e * 257 + tid] = T[half * 32 + e];
      __syncthreads();
      int ee = tid >> 3, ff = tid & 7;
      float p1 = 0.f, p2 = 0.f, p3 = 0.f;
      for (int rr = 0; rr < 32; ++rr) {
        float tv = tb[ee * 257 + rr * 8 + ff];
        p1 += qr[rr] * tv; p2 += qr[32 + rr] * tv; p3 += qr[64 + rr] * tv;
      }
      int eg = half * 32 + ee;
      Pout[((size_t)(0 * NB + b) * 64 + eg) * 64 + f0 + ff] = p1;
      Pout[((size_t)(1 * NB + b) * 64 + eg) * 64 + f0 + ff] = p2;
      Pout[((size_t)(2 * NB + b) * 64 + eg) * 64 + f0 + ff] = p3;
    }
  }
}

// ---------------- per-batch norm finalize ----------------
__global__ __launch_bounds__(256) void scale_k(const float* __restrict__ np_, float* __restrict__ sc) {
  int b = threadIdx.x;
  float ss = 0.f;
  #pragma unroll
  for (int c = 0; c < 8; ++c) ss += np_[b * 8 + c];
  float fn = sqrtf(ss);
  fn = fmaxf(fn, 1.0f);              // relu(fn-1)+1
  sc[b] = 1.0f / fn;
}

// ---------------- inference finisher ----------------
__device__ __forceinline__ float wreduce64(float v) {
  #pragma unroll
  for (int o = 32; o > 0; o >>= 1) v += __shfl_xor(v, o);
  return v;
}

__global__ __launch_bounds__(64) void final_k(const float* __restrict__ P, const float* __restrict__ qe1g,
    const float* __restrict__ sc3, const float* __restrict__ lng, const float* __restrict__ lnb,
    const float* __restrict__ Z, float* __restrict__ out) {
  int b = blockIdx.x, f = threadIdx.x;
  __shared__ float vec[64]; __shared__ float s3buf[64];
  float sc = sc3[b];
  const float* qe = qe1g + (size_t)b * 64;
  float sum3 = 0.f;
  for (int k = 0; k < 3; ++k) {
    const float* Pk = P + ((size_t)k * NB + b) * 4096;
    float acc = 0.f;
    if (k == 0) { for (int e = 0; e < 64; ++e) acc += qe[e] * Pk[e * 64 + f]; }
    else        { for (int e = 0; e < 64; ++e) acc += vec[e] * Pk[e * 64 + f]; }
    float x = acc * sc;
    float mean = wreduce64(x) * (1.0f / 64.0f);
    float d = x - mean;
    float var = wreduce64(d * d) * (1.0f / 63.0f);   // ddof=1
    float y = lng[k * 64 + f] * d / (sqrtf(var) + 1e-6f) + lnb[k * 64 + f];
    sum3 += y;
    __syncthreads();
    vec[f] = y;
    __syncthreads();
  }
  s3buf[f] = sum3;
  __syncthreads();
  if (f < 9) {
    float o = 0.f;
    for (int ff = 0; ff < 64; ++ff) o += s3buf[ff] * Z[ff * 9 + f];
    out[(size_t)b * 9 + f] = o;
  }
}

extern "C" void kernel_launch(void* const* d_in, const int* in_sizes, int n_in,
                              void* d_out, int out_size, void* d_ws, size_t ws_size,
                              hipStream_t stream) {
  const int*   story = (const int*)d_in[0];
  const int*   query = (const int*)d_in[1];
  const float* WE    = (const float*)d_in[2];
  const float* PE    = (const float*)d_in[3];
  const float* ueW1  = (const float*)d_in[4];
  const float* ueb1  = (const float*)d_in[5];
  const float* ueW2  = (const float*)d_in[6];
  const float* ueb2  = (const float*)d_in[7];
  const float* urW1  = (const float*)d_in[8];
  const float* urb1  = (const float*)d_in[9];
  const float* urW2  = (const float*)d_in[10];
  const float* urb2  = (const float*)d_in[11];
  const float* fwm   = (const float*)d_in[12];
  const float* ieW1  = (const float*)d_in[13];
  const float* ieb1  = (const float*)d_in[14];
  const float* ieW2  = (const float*)d_in[15];
  const float* ieb2  = (const float*)d_in[16];
  const float* irW1  = (const float*)d_in[17];
  const float* irb1  = (const float*)d_in[18];
  const float* irW2  = (const float*)d_in[19];
  const float* irb2  = (const float*)d_in[20];
  const float* lng   = (const float*)d_in[21];
  const float* lnb   = (const float*)d_in[22];
  const float* Z     = (const float*)d_in[23];
  float* W = (float*)d_ws;
  float* out = (float*)d_out;

  embed_k<<<7936, 128, 0, stream>>>(story, query, WE, PE, W + OF_SENT, W + OF_QEMB);

  // story heads: e1, e2 (ENT), r1..r3 (ROLE) — h buffer reused (stream-serialized)
  mlp_h<<<dim3(480, 4), 256, 0, stream>>>(W + OF_SENT, ueW1,          ueb1,        W + OF_H);
  mlp_o<64><<<dim3(480), 256, 0, stream>>>(W + OF_H,   ueW2,          ueb2,        W + OF_E1);
  mlp_h<<<dim3(480, 4), 256, 0, stream>>>(W + OF_SENT, ueW1 + 65536,  ueb1 + 512,  W + OF_H);
  mlp_o<64><<<dim3(480), 256, 0, stream>>>(W + OF_H,   ueW2 + 32768,  ueb2 + 64,   W + OF_E2);
  mlp_h<<<dim3(480, 4), 256, 0, stream>>>(W + OF_SENT, urW1,          urb1,        W + OF_H);
  mlp_o<32><<<dim3(480), 256, 0, stream>>>(W + OF_H,   urW2,          urb2,        W + OF_R1);
  mlp_h<<<dim3(480, 4), 256, 0, stream>>>(W + OF_SENT, urW1 + 65536,  urb1 + 512,  W + OF_H);
  mlp_o<32><<<dim3(480), 256, 0, stream>>>(W + OF_H,   urW2 + 16384,  urb2 + 32,   W + OF_R2);
  mlp_h<<<dim3(480, 4), 256, 0, stream>>>(W + OF_SENT, urW1 + 131072, urb1 + 1024, W + OF_H);
  mlp_o<32><<<dim3(480), 256, 0, stream>>>(W + OF_H,   urW2 + 32768,  urb2 + 64,   W + OF_R3);

  // query heads: qe1 (ie head0 only; head1 unused), qr1..qr3
  mlp_h<<<dim3(16, 4), 256, 0, stream>>>(W + OF_QEMB, ieW1,          ieb1,        W + OF_H);
  mlp_o<64><<<dim3(16), 256, 0, stream>>>(W + OF_H,   ieW2,          ieb2,        W + OF_QE1);
  mlp_h<<<dim3(16, 4), 256, 0, stream>>>(W + OF_QEMB, irW1,          irb1,        W + OF_H);
  mlp_o<32><<<dim3(16), 256, 0, stream>>>(W + OF_H,   irW2,          irb2,        W + OF_QR1);
  mlp_h<<<dim3(16, 4), 256, 0, stream>>>(W + OF_QEMB, irW1 + 65536,  irb1 + 512,  W + OF_H);
  mlp_o<32><<<dim3(16), 256, 0, stream>>>(W + OF_H,   irW2 + 16384,  irb2 + 32,   W + OF_QR2);
  mlp_h<<<dim3(16, 4), 256, 0, stream>>>(W + OF_QEMB, irW1 + 131072, irb1 + 1024, W + OF_H);
  mlp_o<32><<<dim3(16), 256, 0, stream>>>(W + OF_H,   irW2 + 32768,  irb2 + 64,   W + OF_QR3);

  // 3 TPR layers with deferred norm-scale; layer 2 fuses the qr-contraction (P) and skips tpr write
  dim3 lg(8, NB);
  layer_k<0><<<lg, 256, 0, stream>>>(fwm, W + OF_TPR, W + OF_E1, W + OF_E2, W + OF_R1, W + OF_R2, W + OF_R3,
      W + OF_QR1, W + OF_QR2, W + OF_QR3, W + OF_SC, W + OF_NP, W + OF_P);
  scale_k<<<1, 256, 0, stream>>>(W + OF_NP, W + OF_SC);
  layer_k<1><<<lg, 256, 0, stream>>>(fwm, W + OF_TPR, W + OF_E1, W + OF_E2, W + OF_R1, W + OF_R2, W + OF_R3,
      W + OF_QR1, W + OF_QR2, W + OF_QR3, W + OF_SC, W + OF_NP, W + OF_P);
  scale_k<<<1, 256, 0, stream>>>(W + OF_NP, W + OF_SC + 256);
  layer_k<2><<<lg, 256, 0, stream>>>(fwm, W + OF_TPR, W + OF_E1, W + OF_E2, W + OF_R1, W + OF_R2, W + OF_R3,
      W + OF_QR1, W + OF_QR2, W + OF_QR3, W + OF_SC + 256, W + OF_NP, W + OF_P);
  scale_k<<<1, 256, 0, stream>>>(W + OF_NP, W + OF_SC + 512);

  final_k<<<NB, 64, 0, stream>>>(W + OF_P, W + OF_QE1, W + OF_SC + 512, lng, lnb, Z, out);
}

// Round 2
// 645.374 us; speedup vs baseline: 1.9354x; 1.9354x over previous
//
#include <hip/hip_runtime.h>
#include <hip/hip_bf16.h>

// Sizes
#define NB 256
#define NS 30
#define NW 10
#define SYM 128
#define HID 512
#define ENT 64
#define ROLE 32

// Workspace offsets (floats)
static const size_t OF_SENT = 0;          // 7680*128
static const size_t OF_QEMB = 983040;     // 256*128
static const size_t OF_H    = 1015808;    // 7680*512
static const size_t OF_E1   = 4947968;    // 7680*64
static const size_t OF_E2   = 5439488;
static const size_t OF_R1   = 5931008;    // 7680*32
static const size_t OF_R2   = 6176768;
static const size_t OF_R3   = 6422528;
static const size_t OF_QE1  = 6668288;    // 256*64
static const size_t OF_QR1  = 6684672;    // 256*32
static const size_t OF_QR2  = 6692864;
static const size_t OF_QR3  = 6701056;
static const size_t OF_PP   = 6709248;    // 3 heads * 4 g * 7680 * 64
static const size_t OF_M    = 12607488;   // 256 * 9 * 900
static const size_t OF_FN2  = 14681088;   // 1

__device__ __forceinline__ void fma4(float4& d, float a, const float4& v) {
  d.x += a * v.x; d.y += a * v.y; d.z += a * v.z; d.w += a * v.w;
}
__device__ __forceinline__ float wreduce64(float v) {
  #pragma unroll
  for (int o = 32; o > 0; o >>= 1) v += __shfl_xor(v, o);
  return v;
}

// ---------------- embedding ----------------
__global__ __launch_bounds__(128) void embed_k(const int* __restrict__ story, const int* __restrict__ query,
    const float* __restrict__ WE, const float* __restrict__ PE,
    float* __restrict__ sent, float* __restrict__ qemb) {
  int bs = blockIdx.x; int e = threadIdx.x;
  const int* idx; float* dst;
  if (bs < 7680) { idx = story + (size_t)bs * NW; dst = sent + (size_t)bs * SYM; }
  else           { idx = query + (size_t)(bs - 7680) * NW; dst = qemb + (size_t)(bs - 7680) * SYM; }
  float acc = 0.f;
  #pragma unroll
  for (int w = 0; w < NW; ++w) {
    int t = idx[w];
    acc += WE[t * SYM + e] * PE[w * SYM + e];
  }
  dst[e] = acc;
}

// ---------------- MLP stage 1 ----------------
__global__ __launch_bounds__(256) void mlp_h(const float* __restrict__ X, const float* __restrict__ W1,
    const float* __restrict__ b1, float* __restrict__ Hout) {
  __shared__ float xt[16 * 128];
  int r0 = blockIdx.x * 16;
  int c0 = blockIdx.y * 128;
  int tid = threadIdx.x;
  #pragma unroll
  for (int i = 0; i < 8; ++i) { int idx = tid + i * 256; xt[idx] = X[(size_t)r0 * 128 + idx]; }
  __syncthreads();
  int c = c0 + (tid & 127); int grp = tid >> 7;
  float acc[8] = {};
  for (int k = 0; k < 128; ++k) {
    float w = W1[k * 512 + c];
    #pragma unroll
    for (int i = 0; i < 8; ++i) acc[i] += xt[(grp * 8 + i) * 128 + k] * w;
  }
  float bb = b1[c];
  #pragma unroll
  for (int i = 0; i < 8; ++i)
    Hout[(size_t)(r0 + grp * 8 + i) * 512 + c] = tanhf(acc[i] + bb);
}

// ---------------- MLP stage 2 ----------------
template <int O>
__global__ __launch_bounds__(256) void mlp_o(const float* __restrict__ H, const float* __restrict__ W2,
    const float* __restrict__ b2, float* __restrict__ Out) {
  __shared__ float ht[16 * 512];
  int r0 = blockIdx.x * 16; int tid = threadIdx.x;
  #pragma unroll
  for (int i = 0; i < 32; ++i) { int idx = tid + i * 256; ht[idx] = H[(size_t)r0 * 512 + idx]; }
  __syncthreads();
  const int G = 256 / O;
  const int RPG = 16 / G;
  int c = tid % O; int grp = tid / O;
  float acc[RPG] = {};
  for (int k = 0; k < 512; ++k) {
    float w = W2[k * O + c];
    #pragma unroll
    for (int i = 0; i < RPG; ++i) acc[i] += ht[(grp * RPG + i) * 512 + k] * w;
  }
  float bb = b2[c];
  #pragma unroll
  for (int i = 0; i < RPG; ++i)
    Out[(size_t)(r0 + grp * RPG + i) * O + c] = tanhf(acc[i] + bb);
}

// ---------------- ||fwm||^2 ----------------
__global__ __launch_bounds__(256) void fnorm_k(const float* __restrict__ fwm, float* __restrict__ o) {
  __shared__ float red[4];
  int tid = threadIdx.x;
  const float4* f4 = reinterpret_cast<const float4*>(fwm);
  float a = 0.f;
  for (int i = tid; i < 32768; i += 256) {
    float4 v = f4[i];
    a += v.x*v.x + v.y*v.y + v.z*v.z + v.w*v.w;
  }
  #pragma unroll
  for (int off = 32; off > 0; off >>= 1) a += __shfl_down(a, off);
  if ((tid & 63) == 0) red[tid >> 6] = a;
  __syncthreads();
  if (tid == 0) o[0] = red[0] + red[1] + red[2] + red[3];
}

// ---------------- P-stage ----------------
__global__ __launch_bounds__(256) void pstage_k(const float* __restrict__ fwm,
    const float* __restrict__ e1g, const float* __restrict__ e2g,
    const float* __restrict__ r1g, const float* __restrict__ r2g, const float* __restrict__ r3g,
    float* __restrict__ Pp) {
  __shared__ float fwmT[64 * 128];
  __shared__ float e1t[16 * 65], e2t[16 * 65];
  __shared__ float r1t[128], r2t[128], r3t[128];
  int rb = blockIdx.x, g = blockIdx.y, tid = threadIdx.x;
  int row = tid >> 4, fo = tid & 15;
  for (int i = tid; i < 1024; i += 256) {
    int rr = i >> 6, e = i & 63;
    e1t[rr * 65 + e] = e1g[((size_t)rb * 16 + rr) * 64 + e];
    e2t[rr * 65 + e] = e2g[((size_t)rb * 16 + rr) * 64 + e];
  }
  if (tid < 128) {
    int rr = tid >> 3, k = tid & 7;
    r1t[tid] = r1g[((size_t)rb * 16 + rr) * 32 + g * 8 + k];
    r2t[tid] = r2g[((size_t)rb * 16 + rr) * 32 + g * 8 + k];
    r3t[tid] = r3g[((size_t)rb * 16 + rr) * 32 + g * 8 + k];
  }
  float4 P11a = {0,0,0,0}, P21a = {0,0,0,0}, P32a = {0,0,0,0};
  const float4* fwm4 = reinterpret_cast<const float4*>(fwm);
  float4* fT4 = reinterpret_cast<float4*>(fwmT);
  for (int sub = 0; sub < 4; ++sub) {
    __syncthreads();
    for (int i = tid; i < 2048; i += 256) {
      int e = i >> 5, c4 = i & 31;
      fT4[i] = fwm4[(size_t)e * 512 + g * 128 + sub * 32 + c4];
    }
    __syncthreads();
    float4 t10 = {0,0,0,0}, t11 = {0,0,0,0}, t20 = {0,0,0,0}, t21 = {0,0,0,0};
    #pragma unroll 8
    for (int e = 0; e < 64; ++e) {
      float w1 = e1t[row * 65 + e], w2 = e2t[row * 65 + e];
      float4 va = fT4[e * 32 + fo], vb = fT4[e * 32 + 16 + fo];
      fma4(t10, w1, va); fma4(t11, w1, vb);
      fma4(t20, w2, va); fma4(t21, w2, vb);
    }
    int rl = sub * 2;
    float a0 = r1t[row * 8 + rl], a1 = r1t[row * 8 + rl + 1];
    float b0 = r2t[row * 8 + rl], b1 = r2t[row * 8 + rl + 1];
    float c0 = r3t[row * 8 + rl], c1 = r3t[row * 8 + rl + 1];
    fma4(P11a, a0, t10); fma4(P11a, a1, t11);
    fma4(P21a, b0, t10); fma4(P21a, b1, t11);
    fma4(P32a, c0, t20); fma4(P32a, c1, t21);
  }
  float4* Pp4 = reinterpret_cast<float4*>(Pp);
  size_t base = (size_t)g * 122880 + ((size_t)rb * 16 + row) * 16 + fo;
  Pp4[base] = P11a;
  Pp4[491520 + base] = P21a;
  Pp4[2 * 491520 + base] = P32a;
}

// ---------------- Gram/M kernel ----------------
__global__ __launch_bounds__(256) void gram_k(const float* __restrict__ e1g, const float* __restrict__ e2g,
    const float* __restrict__ r1g, const float* __restrict__ r2g, const float* __restrict__ r3g,
    float* __restrict__ Mg) {
  __shared__ float e1L[1920], e2L[1920], r1L[960], r2L[960], r3L[960];
  int b = blockIdx.x, tid = threadIdx.x;
  for (int i = tid; i < 1920; i += 256) { e1L[i] = e1g[(size_t)b * 1920 + i]; e2L[i] = e2g[(size_t)b * 1920 + i]; }
  for (int i = tid; i < 960; i += 256) {
    r1L[i] = r1g[(size_t)b * 960 + i]; r2L[i] = r2g[(size_t)b * 960 + i]; r3L[i] = r3g[(size_t)b * 960 + i];
  }
  __syncthreads();
  for (int p = tid; p < 900; p += 256) {
    int si = p / 30, sj = p % 30;
    float g11 = 0, g12 = 0, g21 = 0, g22 = 0;
    for (int e = 0; e < 64; ++e) {
      float a1 = e1L[si * 64 + e], a2 = e2L[si * 64 + e];
      float c1 = e1L[sj * 64 + e], c2 = e2L[sj * 64 + e];
      g11 += a1 * c1; g12 += a1 * c2; g21 += a2 * c1; g22 += a2 * c2;
    }
    float R11=0,R12=0,R13=0,R21=0,R22=0,R23=0,R31=0,R32=0,R33=0;
    for (int r = 0; r < 32; ++r) {
      float x1 = r1L[si * 32 + r], x2 = r2L[si * 32 + r], x3 = r3L[si * 32 + r];
      float y1 = r1L[sj * 32 + r], y2 = r2L[sj * 32 + r], y3 = r3L[sj * 32 + r];
      R11 += x1*y1; R12 += x1*y2; R13 += x1*y3;
      R21 += x2*y1; R22 += x2*y2; R23 += x2*y3;
      R31 += x3*y1; R32 += x3*y2; R33 += x3*y3;
    }
    size_t o = (size_t)b * 8100 + p;
    Mg[o         ] = g11 * R11;   // M11
    Mg[o + 900   ] = g11 * R12;   // M12
    Mg[o + 1800  ] = g12 * R13;   // M13
    Mg[o + 2700  ] = g11 * R21;   // M21
    Mg[o + 3600  ] = g11 * R22;   // M22
    Mg[o + 4500  ] = g12 * R23;   // M23
    Mg[o + 5400  ] = g21 * R31;   // M31
    Mg[o + 6300  ] = g21 * R32;   // M32
    Mg[o + 7200  ] = g22 * R33;   // M33
  }
}

// ---------------- scan + inference ----------------
__global__ __launch_bounds__(256) void scan_k(
    const float* __restrict__ Mg, const float* __restrict__ Pp,
    const float* __restrict__ e1g, const float* __restrict__ e2g,
    const float* __restrict__ r1g, const float* __restrict__ r2g, const float* __restrict__ r3g,
    const float* __restrict__ qe1g, const float* __restrict__ qr1g, const float* __restrict__ qr2g,
    const float* __restrict__ qr3g, const float* __restrict__ fn2p, const float* __restrict__ fwm,
    const float* __restrict__ lng, const float* __restrict__ lnb, const float* __restrict__ Zg,
    float* __restrict__ out) {
  __shared__ float ML[8100];
  __shared__ float e1L[1920], e2L[1920];
  __shared__ float v1L[1920], v2L[1920], v3L[1920];
  __shared__ float zL[32 * 65];
  __shared__ float uv[64], qv[32], alf[96], siL[64];
  __shared__ float redL[4], scal[2];
  int b = blockIdx.x, tid = threadIdx.x;
  int s = tid >> 3, fo = tid & 7;
  bool act = s < 30;
  for (int i = tid; i < 8100; i += 256) ML[i] = Mg[(size_t)b * 8100 + i];
  for (int i = tid; i < 1920; i += 256) { e1L[i] = e1g[(size_t)b * 1920 + i]; e2L[i] = e2g[(size_t)b * 1920 + i]; }
  float H1[8], H2[8], H3[8], a1[8], a2[8], a3[8];
  float n2 = fn2p[0], c0 = 1.f;
  #pragma unroll
  for (int j = 0; j < 8; ++j) { H1[j]=0; H2[j]=0; H3[j]=0; a1[j]=0; a2[j]=0; a3[j]=0; }
  if (act) {
    size_t base = ((size_t)b * 30 + s) * 64 + fo * 8;
    for (int g = 0; g < 4; ++g) {
      size_t o = (size_t)g * 491520 + base;
      #pragma unroll
      for (int j = 0; j < 8; ++j) {
        H1[j] += Pp[o + j];
        H2[j] += Pp[1966080 + o + j];
        H3[j] += Pp[2 * 1966080 + o + j];
      }
    }
  }
  __syncthreads();

  for (int layer = 0; layer < 3; ++layer) {
    float w[8], H2s[8], H3s[8], v1r[8], v2r[8], v3r[8];
    if (act) {
      #pragma unroll
      for (int j = 0; j < 8; ++j) {
        w[j] = H1[j]; H2s[j] = H2[j]; H3s[j] = H3[j];
        v1r[j] = e2L[s * 64 + fo * 8 + j] - H1[j];
        v1L[s * 64 + fo * 8 + j] = v1r[j];
      }
    }
    __syncthreads();
    if (act) {
      for (int sp = 0; sp < 30; ++sp) {
        float m1 = ML[s * 30 + sp], m2 = ML[2700 + s * 30 + sp], m3 = ML[5400 + s * 30 + sp];
        const float* vv = &v1L[sp * 64 + fo * 8];
        #pragma unroll
        for (int j = 0; j < 8; ++j) { float x = vv[j]; H1[j] += m1 * x; H2[j] += m2 * x; H3[j] += m3 * x; }
      }
      #pragma unroll
      for (int j = 0; j < 8; ++j) { v2r[j] = w[j] - H2[j]; v2L[s * 64 + fo * 8 + j] = v2r[j]; }
    }
    __syncthreads();
    if (act) {
      for (int sp = 0; sp < 30; ++sp) {
        float m1 = ML[900 + s * 30 + sp], m2 = ML[3600 + s * 30 + sp], m3 = ML[6300 + s * 30 + sp];
        const float* vv = &v2L[sp * 64 + fo * 8];
        #pragma unroll
        for (int j = 0; j < 8; ++j) { float x = vv[j]; H1[j] += m1 * x; H2[j] += m2 * x; H3[j] += m3 * x; }
      }
      #pragma unroll
      for (int j = 0; j < 8; ++j) { v3r[j] = e1L[s * 64 + fo * 8 + j] - H3[j]; v3L[s * 64 + fo * 8 + j] = v3r[j]; }
    }
    __syncthreads();
    float local = 0.f;
    if (act) {
      for (int sp = 0; sp < 30; ++sp) {
        float m1 = ML[1800 + s * 30 + sp], m2 = ML[4500 + s * 30 + sp], m3 = ML[7200 + s * 30 + sp];
        const float* vv = &v3L[sp * 64 + fo * 8];
        #pragma unroll
        for (int j = 0; j < 8; ++j) { float x = vv[j]; H1[j] += m1 * x; H2[j] += m2 * x; H3[j] += m3 * x; }
      }
      #pragma unroll
      for (int j = 0; j < 8; ++j) { a1[j] += v1r[j]; a2[j] += v2r[j]; a3[j] += v3r[j]; }
      float cr = 0.f;
      #pragma unroll
      for (int j = 0; j < 8; ++j) cr += w[j] * v1r[j] + H2s[j] * v2r[j] + H3s[j] * v3r[j];
      float dt2 = 0.f;
      for (int sp = 0; sp < 30; ++sp) {
        const float* p1 = &v1L[sp * 64 + fo * 8];
        const float* p2 = &v2L[sp * 64 + fo * 8];
        const float* p3 = &v3L[sp * 64 + fo * 8];
        float d11=0,d22=0,d33=0,d12=0,d13=0,d23=0;
        #pragma unroll
        for (int j = 0; j < 8; ++j) {
          float x1 = v1r[j], x2 = v2r[j], x3 = v3r[j];
          float y1 = p1[j], y2 = p2[j], y3 = p3[j];
          d11 += x1*y1; d22 += x2*y2; d33 += x3*y3;
          d12 += x1*y2; d13 += x1*y3; d23 += x2*y3;
        }
        int o = s * 30 + sp;
        dt2 += ML[o]*d11 + ML[3600 + o]*d22 + ML[7200 + o]*d33
             + 2.f*(ML[900 + o]*d12 + ML[1800 + o]*d13 + ML[4500 + o]*d23);
      }
      local = 2.f * cr + dt2;
    }
    #pragma unroll
    for (int o = 32; o > 0; o >>= 1) local += __shfl_down(local, o);
    if ((tid & 63) == 0) redL[tid >> 6] = local;
    __syncthreads();
    if (tid == 0) {
      float tot = n2 + redL[0] + redL[1] + redL[2] + redL[3];
      float fn = fmaxf(sqrtf(tot), 1.f);
      scal[0] = 1.f / fn; scal[1] = tot;
    }
    __syncthreads();
    float inv = scal[0]; n2 = scal[1] * inv * inv; c0 *= inv;
    if (act) {
      #pragma unroll
      for (int j = 0; j < 8; ++j) { H1[j]*=inv; H2[j]*=inv; H3[j]*=inv; a1[j]*=inv; a2[j]*=inv; a3[j]*=inv; }
    }
    __syncthreads();
  }

  // inference
  if (act) {
    #pragma unroll
    for (int j = 0; j < 8; ++j) {
      v1L[s * 64 + fo * 8 + j] = a1[j];
      v2L[s * 64 + fo * 8 + j] = a2[j];
      v3L[s * 64 + fo * 8 + j] = a3[j];
    }
  }
  if (tid < 64) { uv[tid] = qe1g[(size_t)b * 64 + tid]; siL[tid] = 0.f; }
  int r = tid >> 3;
  for (int st = 0; st < 3; ++st) {
    const float* qrg = (st == 0) ? qr1g : ((st == 1) ? qr2g : qr3g);
    if (tid < 32) qv[tid] = qrg[(size_t)b * 32 + tid];
    __syncthreads();
    if (tid < 30) {
      float eu1 = 0, eu2 = 0;
      for (int e = 0; e < 64; ++e) { float u = uv[e]; eu1 += e1L[tid * 64 + e] * u; eu2 += e2L[tid * 64 + e] * u; }
      float rq1 = 0, rq2 = 0, rq3 = 0;
      size_t rbase = ((size_t)b * 30 + tid) * 32;
      for (int rr = 0; rr < 32; ++rr) {
        float q = qv[rr];
        rq1 += r1g[rbase + rr] * q; rq2 += r2g[rbase + rr] * q; rq3 += r3g[rbase + rr] * q;
      }
      alf[tid] = eu1 * rq1; alf[32 + tid] = eu1 * rq2; alf[64 + tid] = eu2 * rq3;
    }
    float z[8] = {};
    {
      int ff = fo * 8;
      for (int e = 0; e < 64; ++e) {
        float u = uv[e];
        const float* fr = &fwm[(size_t)e * 2048 + r * 64 + ff];
        #pragma unroll
        for (int j = 0; j < 8; ++j) z[j] += u * fr[j];
      }
    }
    __syncthreads();
    {
      float q = qv[r];
      #pragma unroll
      for (int j = 0; j < 8; ++j) zL[r * 65 + fo * 8 + j] = q * z[j];
    }
    __syncthreads();
    if (tid < 64) {
      float F = 0.f;
      for (int rr = 0; rr < 32; ++rr) F += zL[rr * 65 + tid];
      float raw = c0 * F;
      for (int sp = 0; sp < 30; ++sp)
        raw += alf[sp] * v1L[sp * 64 + tid] + alf[32 + sp] * v2L[sp * 64 + tid] + alf[64 + sp] * v3L[sp * 64 + tid];
      float mean = wreduce64(raw) * (1.f / 64.f);
      float d = raw - mean;
      float var = wreduce64(d * d) * (1.f / 63.f);
      float y = lng[st * 64 + tid] * d / (sqrtf(var) + 1e-6f) + lnb[st * 64 + tid];
      siL[tid] += y;
      uv[tid] = y;
    }
    __syncthreads();
  }
  if (tid < 9) {
    float o = 0.f;
    for (int ff = 0; ff < 64; ++ff) o += siL[ff] * Zg[ff * 9 + tid];
    out[(size_t)b * 9 + tid] = o;
  }
}

extern "C" void kernel_launch(void* const* d_in, const int* in_sizes, int n_in,
                              void* d_out, int out_size, void* d_ws, size_t ws_size,
                              hipStream_t stream) {
  const int*   story = (const int*)d_in[0];
  const int*   query = (const int*)d_in[1];
  const float* WE    = (const float*)d_in[2];
  const float* PE    = (const float*)d_in[3];
  const float* ueW1  = (const float*)d_in[4];
  const float* ueb1  = (const float*)d_in[5];
  const float* ueW2  = (const float*)d_in[6];
  const float* ueb2  = (const float*)d_in[7];
  const float* urW1  = (const float*)d_in[8];
  const float* urb1  = (const float*)d_in[9];
  const float* urW2  = (const float*)d_in[10];
  const float* urb2  = (const float*)d_in[11];
  const float* fwm   = (const float*)d_in[12];
  const float* ieW1  = (const float*)d_in[13];
  const float* ieb1  = (const float*)d_in[14];
  const float* ieW2  = (const float*)d_in[15];
  const float* ieb2  = (const float*)d_in[16];
  const float* irW1  = (const float*)d_in[17];
  const float* irb1  = (const float*)d_in[18];
  const float* irW2  = (const float*)d_in[19];
  const float* irb2  = (const float*)d_in[20];
  const float* lng   = (const float*)d_in[21];
  const float* lnb   = (const float*)d_in[22];
  const float* Z     = (const float*)d_in[23];
  float* W = (float*)d_ws;
  float* out = (float*)d_out;

  embed_k<<<7936, 128, 0, stream>>>(story, query, WE, PE, W + OF_SENT, W + OF_QEMB);

  mlp_h<<<dim3(480, 4), 256, 0, stream>>>(W + OF_SENT, ueW1,          ueb1,        W + OF_H);
  mlp_o<64><<<dim3(480), 256, 0, stream>>>(W + OF_H,   ueW2,          ueb2,        W + OF_E1);
  mlp_h<<<dim3(480, 4), 256, 0, stream>>>(W + OF_SENT, ueW1 + 65536,  ueb1 + 512,  W + OF_H);
  mlp_o<64><<<dim3(480), 256, 0, stream>>>(W + OF_H,   ueW2 + 32768,  ueb2 + 64,   W + OF_E2);
  mlp_h<<<dim3(480, 4), 256, 0, stream>>>(W + OF_SENT, urW1,          urb1,        W + OF_H);
  mlp_o<32><<<dim3(480), 256, 0, stream>>>(W + OF_H,   urW2,          urb2,        W + OF_R1);
  mlp_h<<<dim3(480, 4), 256, 0, stream>>>(W + OF_SENT, urW1 + 65536,  urb1 + 512,  W + OF_H);
  mlp_o<32><<<dim3(480), 256, 0, stream>>>(W + OF_H,   urW2 + 16384,  urb2 + 32,   W + OF_R2);
  mlp_h<<<dim3(480, 4), 256, 0, stream>>>(W + OF_SENT, urW1 + 131072, urb1 + 1024, W + OF_H);
  mlp_o<32><<<dim3(480), 256, 0, stream>>>(W + OF_H,   urW2 + 32768,  urb2 + 64,   W + OF_R3);

  mlp_h<<<dim3(16, 4), 256, 0, stream>>>(W + OF_QEMB, ieW1,          ieb1,        W + OF_H);
  mlp_o<64><<<dim3(16), 256, 0, stream>>>(W + OF_H,   ieW2,          ieb2,        W + OF_QE1);
  mlp_h<<<dim3(16, 4), 256, 0, stream>>>(W + OF_QEMB, irW1,          irb1,        W + OF_H);
  mlp_o<32><<<dim3(16), 256, 0, stream>>>(W + OF_H,   irW2,          irb2,        W + OF_QR1);
  mlp_h<<<dim3(16, 4), 256, 0, stream>>>(W + OF_QEMB, irW1 + 65536,  irb1 + 512,  W + OF_H);
  mlp_o<32><<<dim3(16), 256, 0, stream>>>(W + OF_H,   irW2 + 16384,  irb2 + 32,   W + OF_QR2);
  mlp_h<<<dim3(16, 4), 256, 0, stream>>>(W + OF_QEMB, irW1 + 131072, irb1 + 1024, W + OF_H);
  mlp_o<32><<<dim3(16), 256, 0, stream>>>(W + OF_H,   irW2 + 32768,  irb2 + 64,   W + OF_QR3);

  fnorm_k<<<1, 256, 0, stream>>>(fwm, W + OF_FN2);
  pstage_k<<<dim3(480, 4), 256, 0, stream>>>(fwm, W + OF_E1, W + OF_E2, W + OF_R1, W + OF_R2, W + OF_R3, W + OF_PP);
  gram_k<<<NB, 256, 0, stream>>>(W + OF_E1, W + OF_E2, W + OF_R1, W + OF_R2, W + OF_R3, W + OF_M);
  scan_k<<<NB, 256, 0, stream>>>(W + OF_M, W + OF_PP, W + OF_E1, W + OF_E2, W + OF_R1, W + OF_R2, W + OF_R3,
      W + OF_QE1, W + OF_QR1, W + OF_QR2, W + OF_QR3, W + OF_FN2, fwm, lng, lnb, Z, out);
}